// Round 1
// baseline (2253.988 us; speedup 1.0000x reference)
//
#include <hip/hip_runtime.h>
#include <math.h>

// Problem constants (reference: S,B,I,H = 1024,512,5,32; G=4H=128)
#define S_LEN 1024
#define BATCH 512
#define HID   32
#define GATES 128

__device__ __forceinline__ float fast_rcp(float x) { return __builtin_amdgcn_rcpf(x); }

__device__ __forceinline__ float sigmoid_f(float x) {
    // 1/(1+e^-x); e^-x -> inf for very negative x gives 0 (correct limit)
    return fast_rcp(1.0f + __expf(-x));
}

__device__ __forceinline__ float tanh_f(float x) {
    // overflow-safe: t = e^{-2|x|} in (0,1]; tanh = sign(x)*(1-t)/(1+t)
    float t = __expf(-2.0f * fabsf(x));
    float r = (1.0f - t) * fast_rcp(1.0f + t);
    return copysignf(r, x);
}

// One block per batch element; 128 threads, thread g owns gate g.
// x: [S, BATCH, KIN]  (may alias out for in-place layers)
// out: [S, BATCH, HID]
// Weights: Wih [128,KIN], Whh [128,32] row-major; gate order i,f,g,o.
template <int KIN>
__global__ __launch_bounds__(GATES)
void lstm_layer_kernel(const float* x, const float* __restrict__ Wih,
                       const float* __restrict__ Whh,
                       const float* __restrict__ bih,
                       const float* __restrict__ bhh, float* out)
{
    const int b = blockIdx.x;
    const int g = threadIdx.x;

    alignas(16) __shared__ float xbuf[(KIN + 7) & ~7];
    alignas(16) __shared__ float hbuf[HID];
    alignas(16) __shared__ float gbuf[GATES];

    // Per-thread weights in registers
    float wih[KIN];
#pragma unroll
    for (int k = 0; k < KIN; ++k) wih[k] = Wih[g * KIN + k];
    float whh[HID];
#pragma unroll
    for (int k = 0; k < HID; ++k) whh[k] = Whh[g * HID + k];
    const float bias = bih[g] + bhh[g];

    float c = 0.0f;
    if (g < HID) hbuf[g] = 0.0f;

    // Prefetch x[0]
    float xnext = (g < KIN) ? x[(size_t)b * KIN + g] : 0.0f;

    for (int s = 0; s < S_LEN; ++s) {
        if (g < KIN) xbuf[g] = xnext;
        __syncthreads();  // hbuf (from s-1) and xbuf (this s) visible

        // Prefetch next step's x (address s+1; never written until iter s+1 -> in-place safe)
        if (g < KIN && s + 1 < S_LEN)
            xnext = x[((size_t)(s + 1) * BATCH + b) * KIN + g];

        // gates[g] = bias + sum_k x[k]*Wih[g,k] + sum_k h[k]*Whh[g,k]
        float acc = bias;
#pragma unroll
        for (int k = 0; k < KIN; ++k) acc += xbuf[k] * wih[k];

        // 4 independent chains over hbuf via float4 reads (ds_read_b128)
        const float4* h4 = reinterpret_cast<const float4*>(hbuf);
        float ax = 0.f, ay = 0.f, az = 0.f, aw = 0.f;
#pragma unroll
        for (int k4 = 0; k4 < HID / 4; ++k4) {
            float4 hv = h4[k4];
            ax += hv.x * whh[4 * k4 + 0];
            ay += hv.y * whh[4 * k4 + 1];
            az += hv.z * whh[4 * k4 + 2];
            aw += hv.w * whh[4 * k4 + 3];
        }
        acc += (ax + ay) + (az + aw);

        gbuf[g] = acc;
        __syncthreads();  // gates visible

        if (g < HID) {
            float ig = sigmoid_f(gbuf[g]);
            float fg = sigmoid_f(gbuf[HID + g]);
            float gg = tanh_f(gbuf[2 * HID + g]);
            float og = sigmoid_f(gbuf[3 * HID + g]);
            c = fg * c + ig * gg;
            float h = og * tanh_f(c);
            hbuf[g] = h;  // consumed after next top-of-loop barrier
            out[((size_t)s * BATCH + b) * HID + g] = h;
        }
    }
}

// MLP head: per (s,b): y = relu(w3 . (W2 (W1 h + b1) + b2) + b3)
__global__ __launch_bounds__(256)
void mlp_kernel(const float* __restrict__ h, const float* __restrict__ w1,
                const float* __restrict__ b1, const float* __restrict__ w2,
                const float* __restrict__ b2, const float* __restrict__ w3,
                const float* __restrict__ b3, float* __restrict__ out)
{
    __shared__ float W1[HID * HID];
    __shared__ float W2[HID * HID];
    __shared__ float W3[HID];
    __shared__ float B1[HID];
    __shared__ float B2[HID];
    __shared__ float B3s;

    for (int i = threadIdx.x; i < HID * HID; i += blockDim.x) {
        W1[i] = w1[i];
        W2[i] = w2[i];
    }
    if (threadIdx.x < HID) {
        W3[threadIdx.x] = w3[threadIdx.x];
        B1[threadIdx.x] = b1[threadIdx.x];
        B2[threadIdx.x] = b2[threadIdx.x];
    }
    if (threadIdx.x == 0) B3s = b3[0];
    __syncthreads();

    const size_t e = (size_t)blockIdx.x * blockDim.x + threadIdx.x;  // (s*B+b)
    float hv[HID];
    const float4* hp = reinterpret_cast<const float4*>(h + e * HID);
#pragma unroll
    for (int k4 = 0; k4 < HID / 4; ++k4) {
        float4 v = hp[k4];
        hv[4 * k4 + 0] = v.x;
        hv[4 * k4 + 1] = v.y;
        hv[4 * k4 + 2] = v.z;
        hv[4 * k4 + 3] = v.w;
    }

    float y1[HID];
#pragma unroll
    for (int j = 0; j < HID; ++j) {
        float acc = B1[j];
#pragma unroll
        for (int k = 0; k < HID; ++k) acc += W1[j * HID + k] * hv[k];
        y1[j] = acc;
    }
    float y2[HID];
#pragma unroll
    for (int j = 0; j < HID; ++j) {
        float acc = B2[j];
#pragma unroll
        for (int k = 0; k < HID; ++k) acc += W2[j * HID + k] * y1[k];
        y2[j] = acc;
    }
    float acc3 = B3s;
#pragma unroll
    for (int k = 0; k < HID; ++k) acc3 += W3[k] * y2[k];
    out[e] = fmaxf(acc3, 0.0f);
}

extern "C" void kernel_launch(void* const* d_in, const int* in_sizes, int n_in,
                              void* d_out, int out_size, void* d_ws, size_t ws_size,
                              hipStream_t stream)
{
    const float* x    = (const float*)d_in[0];
    const float* Wih0 = (const float*)d_in[1];
    const float* Whh0 = (const float*)d_in[2];
    const float* bih0 = (const float*)d_in[3];
    const float* bhh0 = (const float*)d_in[4];
    const float* Wih1 = (const float*)d_in[5];
    const float* Whh1 = (const float*)d_in[6];
    const float* bih1 = (const float*)d_in[7];
    const float* bhh1 = (const float*)d_in[8];
    const float* Wih2 = (const float*)d_in[9];
    const float* Whh2 = (const float*)d_in[10];
    const float* bih2 = (const float*)d_in[11];
    const float* bhh2 = (const float*)d_in[12];
    const float* w1   = (const float*)d_in[13];
    const float* b1   = (const float*)d_in[14];
    const float* w2   = (const float*)d_in[15];
    const float* b2   = (const float*)d_in[16];
    const float* w3   = (const float*)d_in[17];
    const float* b3   = (const float*)d_in[18];

    // Single [S, BATCH, HID] fp32 buffer (64 MB); layers 1/2 run in-place.
    float* hseq = (float*)d_ws;

    lstm_layer_kernel<5><<<BATCH, GATES, 0, stream>>>(x, Wih0, Whh0, bih0, bhh0, hseq);
    lstm_layer_kernel<HID><<<BATCH, GATES, 0, stream>>>(hseq, Wih1, Whh1, bih1, bhh1, hseq);
    lstm_layer_kernel<HID><<<BATCH, GATES, 0, stream>>>(hseq, Wih2, Whh2, bih2, bhh2, hseq);

    mlp_kernel<<<(S_LEN * BATCH) / 256, 256, 0, stream>>>(hseq, w1, b1, w2, b2, w3, b3,
                                                          (float*)d_out);
}

// Round 2
// 1780.983 us; speedup vs baseline: 1.2656x; 1.2656x over previous
//
#include <hip/hip_runtime.h>
#include <math.h>

// Problem constants (reference: S,B,I,H = 1024,512,5,32; G=4H=128)
#define S_LEN 1024
#define BATCH 512
#define HID   32
#define GATES 128

__device__ __forceinline__ float fast_rcp(float x) { return __builtin_amdgcn_rcpf(x); }

__device__ __forceinline__ float sigmoid_f(float x) {
    return fast_rcp(1.0f + __expf(-x));
}

__device__ __forceinline__ float tanh_f(float x) {
    // overflow-safe: t = e^{-2|x|} in (0,1]; tanh = sign(x)*(1-t)/(1+t)
    float t = __expf(-2.0f * fabsf(x));
    float r = (1.0f - t) * fast_rcp(1.0f + t);
    return copysignf(r, x);
}

__device__ __forceinline__ float bcast(int srcLane, float v) {
    // broadcast lane srcLane's value to all 64 lanes (LDS pipe, no barrier)
    return __int_as_float(__builtin_amdgcn_ds_bpermute(srcLane * 4, __float_as_int(v)));
}

// One WAVE (64 threads) per batch element. No __syncthreads anywhere.
// Lane l owns gates l and l+64 (gate order i,f,g,o):
//   lanes 0-31:  i_j (accA), g_j (accB), j = l
//   lanes 32-63: f_j (accA), o_j (accB), j = l-32
// x: [S, BATCH, KIN] (may alias out: slot (s,b) is read >= 1 iter before written)
// out: [S, BATCH, HID]
template <int KIN>
__global__ __launch_bounds__(64, 1)
void lstm_wave_kernel(const float* x, const float* __restrict__ Wih,
                      const float* __restrict__ Whh,
                      const float* __restrict__ bih,
                      const float* __restrict__ bhh, float* out)
{
    const int b = blockIdx.x;
    const int l = threadIdx.x;   // 0..63
    const int j = l & 31;        // hidden unit
    const bool lowHalf = (l < 32);
    const int gA = l;
    const int gB = l + 64;

    // Per-lane weight rows in registers
    float whhA[HID], whhB[HID];
#pragma unroll
    for (int k = 0; k < HID; ++k) {
        whhA[k] = Whh[gA * HID + k];
        whhB[k] = Whh[gB * HID + k];
    }
    float wihA[KIN], wihB[KIN];
#pragma unroll
    for (int k = 0; k < KIN; ++k) {
        wihA[k] = Wih[gA * KIN + k];
        wihB[k] = Wih[gB * KIN + k];
    }
    const float biasA = bih[gA] + bhh[gA];
    const float biasB = bih[gB] + bhh[gB];

    float h_bc[HID];             // replicated h (all lanes)
#pragma unroll
    for (int k = 0; k < HID; ++k) h_bc[k] = 0.0f;
    float c = 0.0f;              // c_j, redundant in both half-waves

    const float* xbase = x + (size_t)b * KIN;
    float* obase = out + (size_t)b * HID;

    // Prefetch x[0]: lane k (k < KIN) holds x element k
    float xv = (lowHalf && j < KIN) ? xbase[j] : 0.0f;

    for (int s = 0; s < S_LEN; ++s) {
        // Broadcast this step's x to all lanes (LDS pipe)
        float xb[KIN];
#pragma unroll
        for (int k = 0; k < KIN; ++k) xb[k] = bcast(k, xv);

        // Prefetch next step's x (slot s+1 not yet written -> in-place safe)
        float xv_n = 0.0f;
        if (lowHalf && j < KIN && s + 1 < S_LEN)
            xv_n = xbase[(size_t)(s + 1) * BATCH * KIN + j];

        // gates: acc = bias + Wih.x + Whh.h   (4 accumulator chains per gate)
        float aA0 = biasA, aA1 = 0.f, aA2 = 0.f, aA3 = 0.f;
        float aB0 = biasB, aB1 = 0.f, aB2 = 0.f, aB3 = 0.f;
#pragma unroll
        for (int k4 = 0; k4 < HID / 4; ++k4) {
            aA0 += whhA[4 * k4 + 0] * h_bc[4 * k4 + 0];
            aA1 += whhA[4 * k4 + 1] * h_bc[4 * k4 + 1];
            aA2 += whhA[4 * k4 + 2] * h_bc[4 * k4 + 2];
            aA3 += whhA[4 * k4 + 3] * h_bc[4 * k4 + 3];
            aB0 += whhB[4 * k4 + 0] * h_bc[4 * k4 + 0];
            aB1 += whhB[4 * k4 + 1] * h_bc[4 * k4 + 1];
            aB2 += whhB[4 * k4 + 2] * h_bc[4 * k4 + 2];
            aB3 += whhB[4 * k4 + 3] * h_bc[4 * k4 + 3];
        }
#pragma unroll
        for (int k = 0; k < KIN; ++k) {
            if ((k & 3) == 0) { aA0 += wihA[k] * xb[k]; aB0 += wihB[k] * xb[k]; }
            else if ((k & 3) == 1) { aA1 += wihA[k] * xb[k]; aB1 += wihB[k] * xb[k]; }
            else if ((k & 3) == 2) { aA2 += wihA[k] * xb[k]; aB2 += wihB[k] * xb[k]; }
            else { aA3 += wihA[k] * xb[k]; aB3 += wihB[k] * xb[k]; }
        }
        float accA = (aA0 + aA1) + (aA2 + aA3);
        float accB = (aB0 + aB1) + (aB2 + aB3);

        // Exchange halves: lane j <-> lane j+32 (both halves get all 4 gates of unit j)
        float pA = __shfl_xor(accA, 32);
        float pB = __shfl_xor(accB, 32);
        float gi = lowHalf ? accA : pA;
        float gf = lowHalf ? pA : accA;
        float gg = lowHalf ? accB : pB;
        float go = lowHalf ? pB : accB;

        gi = sigmoid_f(gi);
        gf = sigmoid_f(gf);
        gg = tanh_f(gg);
        go = sigmoid_f(go);
        c = gf * c + gi * gg;
        float h = go * tanh_f(c);   // redundant in both halves

        if (lowHalf) obase[(size_t)s * BATCH * HID + j] = h;

        // Broadcast new h (lane k holds h_k) for next step's matvec
#pragma unroll
        for (int k = 0; k < HID; ++k) h_bc[k] = bcast(k, h);

        xv = xv_n;
    }
}

// MLP head: per (s,b): y = relu(w3 . (W2 (W1 h + b1) + b2) + b3)
__global__ __launch_bounds__(256)
void mlp_kernel(const float* __restrict__ h, const float* __restrict__ w1,
                const float* __restrict__ b1, const float* __restrict__ w2,
                const float* __restrict__ b2, const float* __restrict__ w3,
                const float* __restrict__ b3, float* __restrict__ out)
{
    __shared__ float W1[HID * HID];
    __shared__ float W2[HID * HID];
    __shared__ float W3[HID];
    __shared__ float B1[HID];
    __shared__ float B2[HID];
    __shared__ float B3s;

    for (int i = threadIdx.x; i < HID * HID; i += blockDim.x) {
        W1[i] = w1[i];
        W2[i] = w2[i];
    }
    if (threadIdx.x < HID) {
        W3[threadIdx.x] = w3[threadIdx.x];
        B1[threadIdx.x] = b1[threadIdx.x];
        B2[threadIdx.x] = b2[threadIdx.x];
    }
    if (threadIdx.x == 0) B3s = b3[0];
    __syncthreads();

    const size_t e = (size_t)blockIdx.x * blockDim.x + threadIdx.x;  // (s*B+b)
    float hv[HID];
    const float4* hp = reinterpret_cast<const float4*>(h + e * HID);
#pragma unroll
    for (int k4 = 0; k4 < HID / 4; ++k4) {
        float4 v = hp[k4];
        hv[4 * k4 + 0] = v.x;
        hv[4 * k4 + 1] = v.y;
        hv[4 * k4 + 2] = v.z;
        hv[4 * k4 + 3] = v.w;
    }

    float y1[HID];
#pragma unroll
    for (int jj = 0; jj < HID; ++jj) {
        float acc = B1[jj];
#pragma unroll
        for (int k = 0; k < HID; ++k) acc += W1[jj * HID + k] * hv[k];
        y1[jj] = acc;
    }
    float y2[HID];
#pragma unroll
    for (int jj = 0; jj < HID; ++jj) {
        float acc = B2[jj];
#pragma unroll
        for (int k = 0; k < HID; ++k) acc += W2[jj * HID + k] * y1[k];
        y2[jj] = acc;
    }
    float acc3 = B3s;
#pragma unroll
    for (int k = 0; k < HID; ++k) acc3 += W3[k] * y2[k];
    out[e] = fmaxf(acc3, 0.0f);
}

extern "C" void kernel_launch(void* const* d_in, const int* in_sizes, int n_in,
                              void* d_out, int out_size, void* d_ws, size_t ws_size,
                              hipStream_t stream)
{
    const float* x    = (const float*)d_in[0];
    const float* Wih0 = (const float*)d_in[1];
    const float* Whh0 = (const float*)d_in[2];
    const float* bih0 = (const float*)d_in[3];
    const float* bhh0 = (const float*)d_in[4];
    const float* Wih1 = (const float*)d_in[5];
    const float* Whh1 = (const float*)d_in[6];
    const float* bih1 = (const float*)d_in[7];
    const float* bhh1 = (const float*)d_in[8];
    const float* Wih2 = (const float*)d_in[9];
    const float* Whh2 = (const float*)d_in[10];
    const float* bih2 = (const float*)d_in[11];
    const float* bhh2 = (const float*)d_in[12];
    const float* w1   = (const float*)d_in[13];
    const float* b1   = (const float*)d_in[14];
    const float* w2   = (const float*)d_in[15];
    const float* b2   = (const float*)d_in[16];
    const float* w3   = (const float*)d_in[17];
    const float* b3   = (const float*)d_in[18];

    // Single [S, BATCH, HID] fp32 buffer (64 MB); layers 1/2 run in-place.
    float* hseq = (float*)d_ws;

    lstm_wave_kernel<5><<<BATCH, 64, 0, stream>>>(x, Wih0, Whh0, bih0, bhh0, hseq);
    lstm_wave_kernel<HID><<<BATCH, 64, 0, stream>>>(hseq, Wih1, Whh1, bih1, bhh1, hseq);
    lstm_wave_kernel<HID><<<BATCH, 64, 0, stream>>>(hseq, Wih2, Whh2, bih2, bhh2, hseq);

    mlp_kernel<<<(S_LEN * BATCH) / 256, 256, 0, stream>>>(hseq, w1, b1, w2, b2, w3, b3,
                                                          (float*)d_out);
}

// Round 3
// 944.326 us; speedup vs baseline: 2.3869x; 1.8860x over previous
//
#include <hip/hip_runtime.h>
#include <math.h>

// Problem constants (reference: S,B,I,H = 1024,512,5,32; G=4H=128)
#define S_LEN 1024
#define BATCH 512
#define HID   32

__device__ __forceinline__ float fast_rcp(float x) { return __builtin_amdgcn_rcpf(x); }

__device__ __forceinline__ float sigmoid_f(float x) {
    return fast_rcp(1.0f + __expf(-x));
}

__device__ __forceinline__ float tanh_f(float x) {
    // overflow-safe: t = e^{-2|x|} in (0,1]; tanh = sign(x)*(1-t)/(1+t)
    float t = __expf(-2.0f * fabsf(x));
    float r = (1.0f - t) * fast_rcp(1.0f + t);
    return copysignf(r, x);
}

// Fused 3-layer LSTM, software-pipelined across waves.
// Block = 192 threads = 3 waves; wave w = layer w; blockIdx = batch element.
// At tick t, wave w processes step s = t - w. h hand-off between layers goes
// through a double-buffered LDS ring; ONE __syncthreads per tick.
// Lane l owns gates l and l+64 of its layer (order i,f,g,o):
//   lanes 0-31 (j=l):    i_j (accA), g_j (accB)
//   lanes 32-63 (j=l-32): f_j (accA), o_j (accB)
__global__ __launch_bounds__(192, 2)
void lstm3_fused(const float* __restrict__ x,
                 const float* __restrict__ Wih0, const float* __restrict__ Whh0,
                 const float* __restrict__ bih0, const float* __restrict__ bhh0,
                 const float* __restrict__ Wih1, const float* __restrict__ Whh1,
                 const float* __restrict__ bih1, const float* __restrict__ bhh1,
                 const float* __restrict__ Wih2, const float* __restrict__ Whh2,
                 const float* __restrict__ bih2, const float* __restrict__ bhh2,
                 float* __restrict__ hseq)
{
    const int b = blockIdx.x;
    const int w = threadIdx.x >> 6;   // wave id == layer id, 0..2
    const int l = threadIdx.x & 63;
    const int j = l & 31;
    const bool lowHalf = (l < 32);
    const int gA = l;
    const int gB = l + 64;

    // ring[parity][slot][unit]; slot w+1 holds layer w's h. Slot 0 unused (zeros).
    __shared__ float ring[2][4][HID];
    for (int i = threadIdx.x; i < 2 * 4 * HID; i += 192)
        (&ring[0][0][0])[i] = 0.0f;

    const float* Wih = (w == 0) ? Wih0 : (w == 1) ? Wih1 : Wih2;
    const float* Whh = (w == 0) ? Whh0 : (w == 1) ? Whh1 : Whh2;
    const float* bih = (w == 0) ? bih0 : (w == 1) ? bih1 : bih2;
    const float* bhh = (w == 0) ? bhh0 : (w == 1) ? bhh1 : bhh2;

    // Recurrent weight rows in registers (all waves)
    float whhA[HID], whhB[HID];
#pragma unroll
    for (int k = 0; k < HID; ++k) {
        whhA[k] = Whh[gA * HID + k];
        whhB[k] = Whh[gB * HID + k];
    }
    // Input weight rows: wave 0 has KIN=5, waves 1/2 have KIN=32.
    float wihA[HID], wihB[HID];
    if (w == 0) {
#pragma unroll
        for (int k = 0; k < 5; ++k) {
            wihA[k] = Wih[gA * 5 + k];
            wihB[k] = Wih[gB * 5 + k];
        }
    } else {
#pragma unroll
        for (int k = 0; k < HID; ++k) {
            wihA[k] = Wih[gA * HID + k];
            wihB[k] = Wih[gB * HID + k];
        }
    }
    const float biasA = bih[gA] + bhh[gA];
    const float biasB = bih[gB] + bhh[gB];

    float c = 0.0f;

    // Wave 0: prefetch x[s=0] (all lanes load same addresses -> L1 broadcast)
    const float* xb0 = x + (size_t)b * 5;
    float xv0 = 0.f, xv1 = 0.f, xv2 = 0.f, xv3 = 0.f, xv4 = 0.f;
    if (w == 0) {
        xv0 = xb0[0]; xv1 = xb0[1]; xv2 = xb0[2]; xv3 = xb0[3]; xv4 = xb0[4];
    }

    __syncthreads();  // ring zero-init visible

    for (int t = 0; t < S_LEN + 2; ++t) {
        const int s = t - w;
        const bool active = (s >= 0) && (s < S_LEN);
        const int p = t & 1;

        // ---- gate matvecs: acc = bias + Whh*h_own + Wih*input ----
        float aA0 = biasA, aA1 = 0.f, aA2 = 0.f, aA3 = 0.f;
        float aB0 = biasB, aB1 = 0.f, aB2 = 0.f, aB3 = 0.f;

        // own h from LDS (written by this wave last tick), same-addr broadcast reads
        const float4* hown4 = reinterpret_cast<const float4*>(&ring[p][w + 1][0]);
#pragma unroll
        for (int k4 = 0; k4 < HID / 4; ++k4) {
            float4 hv = hown4[k4];
            aA0 += whhA[4 * k4 + 0] * hv.x;
            aA1 += whhA[4 * k4 + 1] * hv.y;
            aA2 += whhA[4 * k4 + 2] * hv.z;
            aA3 += whhA[4 * k4 + 3] * hv.w;
            aB0 += whhB[4 * k4 + 0] * hv.x;
            aB1 += whhB[4 * k4 + 1] * hv.y;
            aB2 += whhB[4 * k4 + 2] * hv.z;
            aB3 += whhB[4 * k4 + 3] * hv.w;
        }

        if (w == 0) {
            // direct x input, K=5, values already in regs
            aA0 += wihA[0] * xv0; aB0 += wihB[0] * xv0;
            aA1 += wihA[1] * xv1; aB1 += wihB[1] * xv1;
            aA2 += wihA[2] * xv2; aB2 += wihB[2] * xv2;
            aA3 += wihA[3] * xv3; aB3 += wihB[3] * xv3;
            aA0 += wihA[4] * xv4; aB0 += wihB[4] * xv4;
            // prefetch next step's x
            if (s + 1 < S_LEN) {
                const float* xn = xb0 + (size_t)(s + 1) * BATCH * 5;
                xv0 = xn[0]; xv1 = xn[1]; xv2 = xn[2]; xv3 = xn[3]; xv4 = xn[4];
            }
        } else {
            // input = previous layer's h from LDS ring
            const float4* hin4 = reinterpret_cast<const float4*>(&ring[p][w][0]);
#pragma unroll
            for (int k4 = 0; k4 < HID / 4; ++k4) {
                float4 hv = hin4[k4];
                aA0 += wihA[4 * k4 + 0] * hv.x;
                aA1 += wihA[4 * k4 + 1] * hv.y;
                aA2 += wihA[4 * k4 + 2] * hv.z;
                aA3 += wihA[4 * k4 + 3] * hv.w;
                aB0 += wihB[4 * k4 + 0] * hv.x;
                aB1 += wihB[4 * k4 + 1] * hv.y;
                aB2 += wihB[4 * k4 + 2] * hv.z;
                aB3 += wihB[4 * k4 + 3] * hv.w;
            }
        }
        float accA = (aA0 + aA1) + (aA2 + aA3);
        float accB = (aB0 + aB1) + (aB2 + aB3);

        // ---- exchange halves: both halves get all 4 gates of unit j ----
        float pA = __shfl_xor(accA, 32);
        float pB = __shfl_xor(accB, 32);
        float gi = lowHalf ? accA : pA;
        float gf = lowHalf ? pA : accA;
        float gg = lowHalf ? accB : pB;
        float go = lowHalf ? pB : accB;

        gi = sigmoid_f(gi);
        gf = sigmoid_f(gf);
        gg = tanh_f(gg);
        go = sigmoid_f(go);
        float c_new = gf * c + gi * gg;
        float h = go * tanh_f(c_new);   // redundant in both halves

        if (active) {
            c = c_new;
            if (lowHalf) {
                ring[p ^ 1][w + 1][j] = h;   // for me + next layer, next tick
                if (w == 2)
                    hseq[((size_t)s * BATCH + b) * HID + j] = h;
            }
        }
        __syncthreads();  // tick boundary: writes(t) visible, reads(t) done
    }
}

// MLP head: per (s,b): y = relu(w3 . (W2 (W1 h + b1) + b2) + b3)
__global__ __launch_bounds__(256)
void mlp_kernel(const float* __restrict__ h, const float* __restrict__ w1,
                const float* __restrict__ b1, const float* __restrict__ w2,
                const float* __restrict__ b2, const float* __restrict__ w3,
                const float* __restrict__ b3, float* __restrict__ out)
{
    __shared__ float W1[HID * HID];
    __shared__ float W2[HID * HID];
    __shared__ float W3[HID];
    __shared__ float B1[HID];
    __shared__ float B2[HID];
    __shared__ float B3s;

    for (int i = threadIdx.x; i < HID * HID; i += blockDim.x) {
        W1[i] = w1[i];
        W2[i] = w2[i];
    }
    if (threadIdx.x < HID) {
        W3[threadIdx.x] = w3[threadIdx.x];
        B1[threadIdx.x] = b1[threadIdx.x];
        B2[threadIdx.x] = b2[threadIdx.x];
    }
    if (threadIdx.x == 0) B3s = b3[0];
    __syncthreads();

    const size_t e = (size_t)blockIdx.x * blockDim.x + threadIdx.x;  // (s*B+b)
    float hv[HID];
    const float4* hp = reinterpret_cast<const float4*>(h + e * HID);
#pragma unroll
    for (int k4 = 0; k4 < HID / 4; ++k4) {
        float4 v = hp[k4];
        hv[4 * k4 + 0] = v.x;
        hv[4 * k4 + 1] = v.y;
        hv[4 * k4 + 2] = v.z;
        hv[4 * k4 + 3] = v.w;
    }

    float y1[HID];
#pragma unroll
    for (int jj = 0; jj < HID; ++jj) {
        float acc = B1[jj];
#pragma unroll
        for (int k = 0; k < HID; ++k) acc += W1[jj * HID + k] * hv[k];
        y1[jj] = acc;
    }
    float y2[HID];
#pragma unroll
    for (int jj = 0; jj < HID; ++jj) {
        float acc = B2[jj];
#pragma unroll
        for (int k = 0; k < HID; ++k) acc += W2[jj * HID + k] * y1[k];
        y2[jj] = acc;
    }
    float acc3 = B3s;
#pragma unroll
    for (int k = 0; k < HID; ++k) acc3 += W3[k] * y2[k];
    out[e] = fmaxf(acc3, 0.0f);
}

extern "C" void kernel_launch(void* const* d_in, const int* in_sizes, int n_in,
                              void* d_out, int out_size, void* d_ws, size_t ws_size,
                              hipStream_t stream)
{
    const float* x    = (const float*)d_in[0];
    const float* Wih0 = (const float*)d_in[1];
    const float* Whh0 = (const float*)d_in[2];
    const float* bih0 = (const float*)d_in[3];
    const float* bhh0 = (const float*)d_in[4];
    const float* Wih1 = (const float*)d_in[5];
    const float* Whh1 = (const float*)d_in[6];
    const float* bih1 = (const float*)d_in[7];
    const float* bhh1 = (const float*)d_in[8];
    const float* Wih2 = (const float*)d_in[9];
    const float* Whh2 = (const float*)d_in[10];
    const float* bih2 = (const float*)d_in[11];
    const float* bhh2 = (const float*)d_in[12];
    const float* w1   = (const float*)d_in[13];
    const float* b1   = (const float*)d_in[14];
    const float* w2   = (const float*)d_in[15];
    const float* b2   = (const float*)d_in[16];
    const float* w3   = (const float*)d_in[17];
    const float* b3   = (const float*)d_in[18];

    // [S, BATCH, HID] fp32 buffer (64 MB) for layer-2 output
    float* hseq = (float*)d_ws;

    lstm3_fused<<<BATCH, 192, 0, stream>>>(x, Wih0, Whh0, bih0, bhh0,
                                           Wih1, Whh1, bih1, bhh1,
                                           Wih2, Whh2, bih2, bhh2, hseq);

    mlp_kernel<<<(S_LEN * BATCH) / 256, 256, 0, stream>>>(hseq, w1, b1, w2, b2, w3, b3,
                                                          (float*)d_out);
}